// Round 6
// baseline (143.532 us; speedup 1.0000x reference)
//
#include <hip/hip_runtime.h>
#include <hip/hip_bf16.h>

#define HID  128
#define NRAD 16
#define NT   100      // atom types (emb rows)

// Workspace: Pbf (bf16 [NT][260], 52000 B) | W3 (32768 B) | WrbfB (4096 B)
// LDS (dynamic):
//   Pl : bf16 [NT][260]  (padded rows -> 2-bank rotate)    52000 B
//   rb : 2 x [128 edges][256 B] swizzled bf16 r-tile       65536 B
//   aL : 2 x [128] int                                      1024 B
//   bL : 2 x [128] int                                      1024 B
#define PL_BYTES   (NT * 260 * 2)
#define RB_OFF     PL_BYTES
#define AL_OFF     (RB_OFF + 2 * 128 * 256)
#define BL_OFF     (AL_OFF + 2 * 512)
#define LDS_BYTES  (BL_OFF + 2 * 512)

typedef __attribute__((ext_vector_type(4))) float f32x4;
typedef __attribute__((ext_vector_type(8))) __bf16 bf16x8;
typedef __attribute__((ext_vector_type(4))) __bf16 bf16x4;

union F8 { bf16x8 b; int4 i4; };
union B4 { bf16x4 b4; int2 i2; };

__device__ inline unsigned short f2bfbits(float f){
  unsigned int u = __float_as_uint(f);
  u += 0x7FFFu + ((u >> 16) & 1u);
  return (unsigned short)(u >> 16);
}

__device__ inline float silu_f(float v){
  return v * __builtin_amdgcn_rcpf(1.0f + __expf(-v));
}

__device__ inline float bflo(int q){ return __uint_as_float((unsigned)q << 16); }
__device__ inline float bfhi(int q){ return __uint_as_float((unsigned)q & 0xFFFF0000u); }

// ---------------------------------------------------------------------------
// Setup: Pbf table (bf16, padded rows), W3 bf16, Wrbf bf16 (one launch)
// ---------------------------------------------------------------------------
__global__ void setup_kernel(const float* __restrict__ emb,
                             const float* __restrict__ W_lin,
                             const float* __restrict__ b_lin,
                             const float* __restrict__ W_rbf,
                             int ntypes,
                             unsigned short* __restrict__ Pbf,
                             unsigned short* __restrict__ W3,
                             unsigned short* __restrict__ WrbfB){
  int blk = blockIdx.x;
  int n = threadIdx.x;                // 0..255
  if (blk < ntypes){
    __shared__ float er[HID];
    if (n < HID) er[n] = emb[blk * HID + n];
    __syncthreads();
    int half = n >> 7, nn = n & 127;
    const float4* w4 = (const float4*)(W_lin + (size_t)nn * (3 * HID) + half * HID);
    float s = half ? 0.0f : b_lin[nn];
    #pragma unroll 8
    for (int k4 = 0; k4 < HID / 4; ++k4){
      float4 w = w4[k4];
      s += er[k4*4+0]*w.x + er[k4*4+1]*w.y + er[k4*4+2]*w.z + er[k4*4+3]*w.w;
    }
    Pbf[blk * 260 + n] = f2bfbits(s);
    if (n < 4) Pbf[blk * 260 + 256 + n] = 0;   // deterministic pad
  } else if (blk < ntypes + 64){
    int idx = (blk - ntypes) * 256 + n;       // 0..16383
    int r = idx >> 7, k = idx & 127;
    W3[idx] = f2bfbits(W_lin[(size_t)r * (3 * HID) + 2 * HID + k]);
  } else {
    int idx = (blk - ntypes - 64) * 256 + n;  // 0..2047
    WrbfB[idx] = f2bfbits(W_rbf[idx]);
  }
}

// ---------------------------------------------------------------------------
// Edge kernel: 512 threads (8 waves), 128 edges/tile, grid-stride,
// single barrier per tile, double-buffered r-tile and index buffers.
// Wave wv: phase1 computes r for edges [wv*16,wv*16+16); phase2 computes
// output n-slice [wv*16, wv*16+16) for ALL 128 edges (W3 slice in regs).
// P table (bf16) in LDS. Wave 0 runs a 2-deep ei/x index pipeline.
// ---------------------------------------------------------------------------
__global__ __launch_bounds__(512) void edge_kernel(
    const float* __restrict__ rbf,
    const int*   __restrict__ ei,
    const int*   __restrict__ ej,
    const int*   __restrict__ x,
    const unsigned short* __restrict__ WrbfB, // bf16 bits, [128][16]
    const float* __restrict__ brbf,
    const unsigned short* __restrict__ Pbf,   // bf16 bits, [NT][260]
    const unsigned short* __restrict__ W3,    // bf16 bits, [128][128]
    float* __restrict__ out,
    int E, int ntile)
{
  extern __shared__ char smem[];
  char*  rb  = smem + RB_OFF;
  int*   aL  = (int*)(smem + AL_OFF);
  int*   bL  = (int*)(smem + BL_OFF);

  const int tid  = threadIdx.x;
  const int lane = tid & 63;
  const int wv   = tid >> 6;        // 0..7
  const int erow = lane & 15;
  const int kgrp = lane >> 4;       // 0..3
  const int G    = gridDim.x;

  // ---- stage Pbf into LDS -------------------------------------------------
  for (int i = tid; i < PL_BYTES / 16; i += 512)
    ((int4*)smem)[i] = ((const int4*)Pbf)[i];

  // ---- loop-invariant register fragments ----------------------------------
  F8 wr[8];                                    // Wrbf rows, all 8 n-tiles
  #pragma unroll
  for (int t = 0; t < 8; ++t){
    wr[t].i4 = make_int4(0, 0, 0, 0);
    if (kgrp < 2) wr[t].i4 = *(const int4*)(WrbfB + (t * 16 + erow) * NRAD + kgrp * 8);
  }
  F8 w3[4];                                    // W3 rows for n-tile wv
  #pragma unroll
  for (int s = 0; s < 4; ++s)
    w3[s].i4 = *(const int4*)(W3 + (wv * 16 + erow) * HID + s * 32 + kgrp * 8);
  float4 bias[8];
  #pragma unroll
  for (int t = 0; t < 8; ++t) bias[t] = *(const float4*)(brbf + t * 16 + kgrp * 4);

  // ---- pipeline prologue ---------------------------------------------------
  int tile = blockIdx.x;
  // wave0 index pipeline: xa/xb = x-values for CURRENT tile; e2/j2 = ei/ej of NEXT tile
  int2 xa = make_int2(0,0), xb = make_int2(0,0);
  int2 e2 = make_int2(0,0), j2 = make_int2(0,0);
  if (tid < 64){
    long i0 = (long)tile * 128 + tid * 2;
    if (i0 > E - 2) i0 = E - 2;
    int2 t0 = *(const int2*)(ei + i0);
    int2 t1 = *(const int2*)(ej + i0);
    xa.x = x[t0.x]; xa.y = x[t0.y];
    xb.x = x[t1.x]; xb.y = x[t1.y];
    if (tile + G < ntile){
      long i1 = (long)(tile + G) * 128 + tid * 2;
      if (i1 > E - 2) i1 = E - 2;
      e2 = *(const int2*)(ei + i1);
      j2 = *(const int2*)(ej + i1);
    }
  }
  // rbf for first tile
  f32x4 f0 = {0,0,0,0}, f1 = {0,0,0,0};
  if (kgrp < 2){
    long ge = (long)tile * 128 + wv * 16 + erow;
    if (ge < E){
      const f32x4* s4 = (const f32x4*)(rbf + ge * NRAD + kgrp * 8);
      f0 = __builtin_nontemporal_load(s4);
      f1 = __builtin_nontemporal_load(s4 + 1);
    }
  }

  __syncthreads();                             // P staged

  int buf = 0;
  while (tile < ntile){
    const long base = (long)tile * 128;
    const int  next = tile + G;
    char* rbc = rb + buf * 32768;
    int*  aLc = aL + buf * 128;
    int*  bLc = bL + buf * 128;

    // wave 0: commit aL/bL for CURRENT tile (values gathered last iter),
    // then advance the index pipeline (x-gathers for next, ei/ej for next+1)
    if (tid < 64){
      *(int2*)(aLc + tid * 2) = xa;
      *(int2*)(bLc + tid * 2) = xb;
      if (next < ntile){
        xa.x = x[e2.x]; xa.y = x[e2.y];
        xb.x = x[j2.x]; xb.y = x[j2.y];
        if (next + G < ntile){
          long i1 = (long)(next + G) * 128 + tid * 2;
          if (i1 > E - 2) i1 = E - 2;
          e2 = *(const int2*)(ei + i1);
          j2 = *(const int2*)(ej + i1);
        }
      }
    }

    // per-wave: prefetch next tile's rbf
    f32x4 nf0 = {0,0,0,0}, nf1 = {0,0,0,0};
    if (next < ntile && kgrp < 2){
      long gn = (long)next * 128 + wv * 16 + erow;
      if (gn < E){
        const f32x4* s4 = (const f32x4*)(rbf + gn * NRAD + kgrp * 8);
        nf0 = __builtin_nontemporal_load(s4);
        nf1 = __builtin_nontemporal_load(s4 + 1);
      }
    }

    // ---- phase 1: r for own 16 edges -> swizzled LDS (buf) ----------------
    const int e_l = wv * 16 + erow;
    F8 fb; fb.i4 = make_int4(0, 0, 0, 0);
    if (kgrp < 2){
      fb.b[0]=(__bf16)f0.x; fb.b[1]=(__bf16)f0.y; fb.b[2]=(__bf16)f0.z; fb.b[3]=(__bf16)f0.w;
      fb.b[4]=(__bf16)f1.x; fb.b[5]=(__bf16)f1.y; fb.b[6]=(__bf16)f1.z; fb.b[7]=(__bf16)f1.w;
    }
    #pragma unroll
    for (int t = 0; t < 8; ++t){
      f32x4 acc = {0.f, 0.f, 0.f, 0.f};
      acc = __builtin_amdgcn_mfma_f32_16x16x32_bf16(wr[t].b, fb.b, acc, 0, 0, 0);
      B4 pk;
      pk.b4[0] = (__bf16)silu_f(acc[0] + bias[t].x);
      pk.b4[1] = (__bf16)silu_f(acc[1] + bias[t].y);
      pk.b4[2] = (__bf16)silu_f(acc[2] + bias[t].z);
      pk.b4[3] = (__bf16)silu_f(acc[3] + bias[t].w);
      int byte = (e_l << 8) + t * 32 + kgrp * 8;
      byte ^= (e_l & 7) << 4;
      *(int2*)(rbc + byte) = pk.i2;
    }

    // single barrier per tile: rb/aL/bL (buf) now complete
    asm volatile("s_waitcnt lgkmcnt(0)" ::: "memory");
    __builtin_amdgcn_s_barrier();

    // ---- phase 2 + epilogue: own n-slice for all 128 edges ----------------
    const int nb = wv * 16 + kgrp * 4;
    const unsigned short* PlU = (const unsigned short*)smem;
    #pragma unroll
    for (int eg = 0; eg < 8; ++eg){
      const int ed = eg * 16 + erow;
      f32x4 acc = {0.f, 0.f, 0.f, 0.f};
      #pragma unroll
      for (int s = 0; s < 4; ++s){
        int byte = (ed << 8) + s * 64 + kgrp * 16;
        byte ^= (ed & 7) << 4;
        F8 bB; bB.i4 = *(const int4*)(rbc + byte);
        acc = __builtin_amdgcn_mfma_f32_16x16x32_bf16(w3[s].b, bB.b, acc, 0, 0, 0);
      }
      int a = aLc[ed], b = bLc[ed];
      int2 q1 = *(const int2*)(PlU + a * 260 + nb);
      int2 q2 = *(const int2*)(PlU + b * 260 + 128 + nb);
      f32x4 o;
      o.x = silu_f(acc[0] + bflo(q1.x) + bflo(q2.x));
      o.y = silu_f(acc[1] + bfhi(q1.x) + bfhi(q2.x));
      o.z = silu_f(acc[2] + bflo(q1.y) + bflo(q2.y));
      o.w = silu_f(acc[3] + bfhi(q1.y) + bfhi(q2.y));
      long ge = base + ed;
      if (ge < E)
        *(f32x4*)(out + ge * HID + nb) = o;
    }

    // rotate pipeline (no second barrier: distance-2 hazard covered by
    // the per-iter barrier + double buffers)
    f0 = nf0; f1 = nf1;
    buf ^= 1;
    tile = next;
  }
}

// ---------------------------------------------------------------------------
extern "C" void kernel_launch(void* const* d_in, const int* in_sizes, int n_in,
                              void* d_out, int out_size, void* d_ws, size_t ws_size,
                              hipStream_t stream){
  const int*   x    = (const int*)  d_in[0];
  const float* rbf  = (const float*)d_in[1];
  const int*   ei   = (const int*)  d_in[2];
  const int*   ej   = (const int*)  d_in[3];
  const float* emb  = (const float*)d_in[4];
  const float* Wrbf = (const float*)d_in[5];
  const float* brbf = (const float*)d_in[6];
  const float* Wlin = (const float*)d_in[7];
  const float* blin = (const float*)d_in[8];
  float* out = (float*)d_out;

  const int E      = in_sizes[2];
  const int ntypes = in_sizes[4] / HID;   // 100

  unsigned short* Pbf   = (unsigned short*)d_ws;
  unsigned short* W3    = (unsigned short*)((char*)d_ws + PL_BYTES);
  unsigned short* WrbfB = (unsigned short*)((char*)W3 + (size_t)HID * HID * sizeof(unsigned short));

  setup_kernel<<<ntypes + 64 + 8, 256, 0, stream>>>(emb, Wlin, blin, Wrbf, ntypes, Pbf, W3, WrbfB);

  (void)hipFuncSetAttribute(reinterpret_cast<const void*>(&edge_kernel),
                            hipFuncAttributeMaxDynamicSharedMemorySize, LDS_BYTES);

  const int ntile = (E + 127) / 128;
  const int nblk  = ntile < 256 ? ntile : 256;
  edge_kernel<<<nblk, 512, LDS_BYTES, stream>>>(rbf, ei, ej, x, WrbfB, brbf, Pbf, W3, out, E, ntile);
}

// Round 7
// 141.063 us; speedup vs baseline: 1.0175x; 1.0175x over previous
//
#include <hip/hip_runtime.h>
#include <hip/hip_bf16.h>

#define HID  128
#define NRAD 16
#define NT   100      // atom types (emb rows)

// LDS (dynamic):
//   Pl : f32 [NT][260] (260-stride -> 4-bank rotate)   104000 B
//   rb : [128 edges][256 B] swizzled bf16 r-tile        32768 B
#define PL_BYTES   (NT * 260 * 4)
#define RB_OFF     PL_BYTES
#define LDS_BYTES  (RB_OFF + 128 * 256)   // 136768

// Workspace layout: P f32 (102400) | W3 (32768) | WrbfB (4096) | xij (E*8)
#define WS_P_BYTES   (NT * 256 * 4)
#define WS_W3_OFF    WS_P_BYTES
#define WS_WRBF_OFF  (WS_W3_OFF + HID * HID * 2)
#define WS_XIJ_OFF   (WS_WRBF_OFF + HID * NRAD * 2 + 1920)  // pad to 16B-aligned 140864... computed below

typedef __attribute__((ext_vector_type(4))) float f32x4;
typedef __attribute__((ext_vector_type(8))) __bf16 bf16x8;
typedef __attribute__((ext_vector_type(4))) __bf16 bf16x4;

union F8 { bf16x8 b; int4 i4; };
union B4 { bf16x4 b4; int2 i2; };

__device__ inline unsigned short f2bfbits(float f){
  unsigned int u = __float_as_uint(f);
  u += 0x7FFFu + ((u >> 16) & 1u);
  return (unsigned short)(u >> 16);
}

__device__ inline float silu_f(float v){
  return v * __builtin_amdgcn_rcpf(1.0f + __expf(-v));
}

// ---------------------------------------------------------------------------
// Setup (one launch):
//   blocks [0, ntypes)            : P[t][0:128]=emb@W1^T+b_lin ; [128:256]=emb@W2^T
//   blocks [ntypes, +64)          : W3 bf16 conversion (128x128)
//   blocks [ntypes+64, +8)        : W_rbf bf16 conversion (128x16)
//   blocks [ntypes+72, ...)       : xij[e] = (x[ei[e]], x[ej[e]])  (if do_xij)
// ---------------------------------------------------------------------------
__global__ void setup_kernel(const float* __restrict__ emb,
                             const float* __restrict__ W_lin,
                             const float* __restrict__ b_lin,
                             const float* __restrict__ W_rbf,
                             const int*   __restrict__ ei,
                             const int*   __restrict__ ej,
                             const int*   __restrict__ x,
                             int ntypes, int E,
                             float* __restrict__ P,
                             unsigned short* __restrict__ W3,
                             unsigned short* __restrict__ WrbfB,
                             int2* __restrict__ xij){
  int blk = blockIdx.x;
  int n = threadIdx.x;                // 0..255
  if (blk < ntypes){
    __shared__ float er[HID];
    if (n < HID) er[n] = emb[blk * HID + n];
    __syncthreads();
    int half = n >> 7, nn = n & 127;
    const float4* w4 = (const float4*)(W_lin + (size_t)nn * (3 * HID) + half * HID);
    float s = half ? 0.0f : b_lin[nn];
    #pragma unroll 8
    for (int k4 = 0; k4 < HID / 4; ++k4){
      float4 w = w4[k4];
      s += er[k4*4+0]*w.x + er[k4*4+1]*w.y + er[k4*4+2]*w.z + er[k4*4+3]*w.w;
    }
    P[blk * 256 + n] = s;
  } else if (blk < ntypes + 64){
    int idx = (blk - ntypes) * 256 + n;       // 0..16383
    int r = idx >> 7, k = idx & 127;
    W3[idx] = f2bfbits(W_lin[(size_t)r * (3 * HID) + 2 * HID + k]);
  } else if (blk < ntypes + 72){
    int idx = (blk - ntypes - 64) * 256 + n;  // 0..2047
    WrbfB[idx] = f2bfbits(W_rbf[idx]);
  } else {
    int idx = (blk - ntypes - 72) * 512 + n * 2;
    if (idx + 1 < E){
      int2 e2 = *(const int2*)(ei + idx);
      int2 j2 = *(const int2*)(ej + idx);
      int4 v;
      v.x = x[e2.x]; v.y = x[j2.x];
      v.z = x[e2.y]; v.w = x[j2.y];
      *(int4*)(xij + idx) = v;
    } else if (idx < E){
      xij[idx] = make_int2(x[ei[idx]], x[ej[idx]]);
    }
  }
}

// ---------------------------------------------------------------------------
// Edge kernel: 512 threads (8 waves), 128 edges/tile, grid-stride.
// Phase 1: wave wv computes r for edges [wv*16, wv*16+16) -> swizzled LDS.
// Phase 2 split (LDS-traffic-minimizing): wave = (edge-group gg = wv>>2,
//   n-group ww = wv&3); computes n in [ww*32, ww*32+32) for edges
//   [gg*64, gg*64+64). rb read per wave: 16 KB (was 32 KB).
// P table f32 in LDS (260-stride). Per-lane xij loads (no wave0 chain).
// ---------------------------------------------------------------------------
__global__ __launch_bounds__(512) void edge_kernel(
    const float* __restrict__ rbf,
    const int*   __restrict__ ei,
    const int*   __restrict__ ej,
    const int*   __restrict__ x,
    const unsigned short* __restrict__ WrbfB, // bf16 bits, [128][16]
    const float* __restrict__ brbf,
    const float* __restrict__ Pg,             // f32 [NT][256]
    const unsigned short* __restrict__ W3,    // bf16 bits, [128][128]
    const int2*  __restrict__ xij,            // may be null
    float* __restrict__ out,
    int E, int ntile, int use_xij)
{
  extern __shared__ char smem[];
  float* Pl = (float*)smem;
  char*  rb = smem + RB_OFF;

  const int tid  = threadIdx.x;
  const int lane = tid & 63;
  const int wv   = tid >> 6;        // 0..7
  const int erow = lane & 15;
  const int kgrp = lane >> 4;       // 0..3
  const int gg   = wv >> 2;         // phase2 edge-group (0/1)
  const int ww   = wv & 3;          // phase2 n-group (0..3)
  const int G    = gridDim.x;

  // ---- stage P into LDS (rows padded to 260 floats) -----------------------
  for (int i = tid; i < NT * 64; i += 512){
    int row = i >> 6, c4 = i & 63;
    *(f32x4*)(Pl + row * 260 + c4 * 4) = *(const f32x4*)(Pg + row * 256 + c4 * 4);
  }

  // ---- loop-invariant register fragments ----------------------------------
  F8 wr[8];                                    // Wrbf rows, all 8 n-tiles (phase1)
  #pragma unroll
  for (int t = 0; t < 8; ++t){
    wr[t].i4 = make_int4(0, 0, 0, 0);
    if (kgrp < 2) wr[t].i4 = *(const int4*)(WrbfB + (t * 16 + erow) * NRAD + kgrp * 8);
  }
  F8 w3[8];                                    // W3 rows for n-tiles ww*2, ww*2+1
  #pragma unroll
  for (int u = 0; u < 2; ++u)
    #pragma unroll
    for (int s = 0; s < 4; ++s)
      w3[u*4+s].i4 = *(const int4*)(W3 + ((ww*2+u)*16 + erow) * HID + s * 32 + kgrp * 8);
  float4 bias[8];
  #pragma unroll
  for (int t = 0; t < 8; ++t) bias[t] = *(const float4*)(brbf + t * 16 + kgrp * 4);

  // ---- prologue: first tile's rbf -----------------------------------------
  int tile = blockIdx.x;
  f32x4 f0 = {0,0,0,0}, f1 = {0,0,0,0};
  if (tile < ntile && kgrp < 2){
    long ge = (long)tile * 128 + wv * 16 + erow;
    if (ge < E){
      const f32x4* s4 = (const f32x4*)(rbf + ge * NRAD + kgrp * 8);
      f0 = __builtin_nontemporal_load(s4);
      f1 = __builtin_nontemporal_load(s4 + 1);
    }
  }

  __syncthreads();                             // P staged

  while (tile < ntile){
    const long base = (long)tile * 128;
    const int  next = tile + G;

    // ---- current tile's (a,b) type indices (phase2 edges), issued early ---
    int2 xv[4];
    #pragma unroll
    for (int eg = 0; eg < 4; ++eg){
      long ge = base + gg * 64 + eg * 16 + erow;
      if (ge > E - 1) ge = E - 1;
      if (use_xij){
        xv[eg] = xij[ge];
      } else {
        xv[eg].x = x[ei[ge]];
        xv[eg].y = x[ej[ge]];
      }
    }

    // ---- prefetch next tile's rbf -----------------------------------------
    f32x4 nf0 = {0,0,0,0}, nf1 = {0,0,0,0};
    if (next < ntile && kgrp < 2){
      long gn = (long)next * 128 + wv * 16 + erow;
      if (gn < E){
        const f32x4* s4 = (const f32x4*)(rbf + gn * NRAD + kgrp * 8);
        nf0 = __builtin_nontemporal_load(s4);
        nf1 = __builtin_nontemporal_load(s4 + 1);
      }
    }

    // ---- phase 1: r for own 16 edges -> swizzled LDS ----------------------
    const int e_l = wv * 16 + erow;
    F8 fb; fb.i4 = make_int4(0, 0, 0, 0);
    if (kgrp < 2){
      fb.b[0]=(__bf16)f0.x; fb.b[1]=(__bf16)f0.y; fb.b[2]=(__bf16)f0.z; fb.b[3]=(__bf16)f0.w;
      fb.b[4]=(__bf16)f1.x; fb.b[5]=(__bf16)f1.y; fb.b[6]=(__bf16)f1.z; fb.b[7]=(__bf16)f1.w;
    }
    #pragma unroll
    for (int t = 0; t < 8; ++t){
      f32x4 acc = {0.f, 0.f, 0.f, 0.f};
      acc = __builtin_amdgcn_mfma_f32_16x16x32_bf16(wr[t].b, fb.b, acc, 0, 0, 0);
      B4 pk;
      pk.b4[0] = (__bf16)silu_f(acc[0] + bias[t].x);
      pk.b4[1] = (__bf16)silu_f(acc[1] + bias[t].y);
      pk.b4[2] = (__bf16)silu_f(acc[2] + bias[t].z);
      pk.b4[3] = (__bf16)silu_f(acc[3] + bias[t].w);
      int byte = (e_l << 8) + t * 32 + kgrp * 8;
      byte ^= (e_l & 7) << 4;
      *(int2*)(rb + byte) = pk.i2;
    }

    asm volatile("s_waitcnt lgkmcnt(0)" ::: "memory");
    __builtin_amdgcn_s_barrier();

    // ---- phase 2 + epilogue: n-slice [ww*32,+32) for edges [gg*64,+64) ----
    #pragma unroll
    for (int eg = 0; eg < 4; ++eg){
      const int ed = gg * 64 + eg * 16 + erow;
      f32x4 a0 = {0.f,0.f,0.f,0.f}, a1 = {0.f,0.f,0.f,0.f};
      #pragma unroll
      for (int s = 0; s < 4; ++s){
        int byte = (ed << 8) + s * 64 + kgrp * 16;
        byte ^= (ed & 7) << 4;
        F8 bB; bB.i4 = *(const int4*)(rb + byte);
        a0 = __builtin_amdgcn_mfma_f32_16x16x32_bf16(w3[s].b,   bB.b, a0, 0, 0, 0);
        a1 = __builtin_amdgcn_mfma_f32_16x16x32_bf16(w3[4+s].b, bB.b, a1, 0, 0, 0);
      }
      const int aT = xv[eg].x, bT = xv[eg].y;
      const long ge = base + ed;
      #pragma unroll
      for (int u = 0; u < 2; ++u){
        f32x4 acc = u ? a1 : a0;
        int nb = (ww * 2 + u) * 16 + kgrp * 4;
        f32x4 p1 = *(const f32x4*)(Pl + aT * 260 + nb);
        f32x4 p2 = *(const f32x4*)(Pl + bT * 260 + 128 + nb);
        f32x4 o;
        o.x = silu_f(acc[0] + p1.x + p2.x);
        o.y = silu_f(acc[1] + p1.y + p2.y);
        o.z = silu_f(acc[2] + p1.z + p2.z);
        o.w = silu_f(acc[3] + p1.w + p2.w);
        if (ge < E)
          *(f32x4*)(out + ge * HID + nb) = o;
      }
    }

    asm volatile("s_waitcnt lgkmcnt(0)" ::: "memory");
    __builtin_amdgcn_s_barrier();

    f0 = nf0; f1 = nf1;
    tile = next;
  }
}

// ---------------------------------------------------------------------------
extern "C" void kernel_launch(void* const* d_in, const int* in_sizes, int n_in,
                              void* d_out, int out_size, void* d_ws, size_t ws_size,
                              hipStream_t stream){
  const int*   x    = (const int*)  d_in[0];
  const float* rbf  = (const float*)d_in[1];
  const int*   ei   = (const int*)  d_in[2];
  const int*   ej   = (const int*)  d_in[3];
  const float* emb  = (const float*)d_in[4];
  const float* Wrbf = (const float*)d_in[5];
  const float* brbf = (const float*)d_in[6];
  const float* Wlin = (const float*)d_in[7];
  const float* blin = (const float*)d_in[8];
  float* out = (float*)d_out;

  const int E      = in_sizes[2];
  const int ntypes = in_sizes[4] / HID;   // 100

  float*          P     = (float*)d_ws;
  unsigned short* W3    = (unsigned short*)((char*)d_ws + WS_P_BYTES);
  unsigned short* WrbfB = (unsigned short*)((char*)d_ws + WS_P_BYTES + HID * HID * 2);
  size_t xij_off = (size_t)WS_P_BYTES + HID * HID * 2 + HID * NRAD * 2;
  xij_off = (xij_off + 15) & ~(size_t)15;
  int2* xij = (int2*)((char*)d_ws + xij_off);

  const int use_xij = (ws_size >= xij_off + (size_t)E * 8) ? 1 : 0;
  const int nxe = use_xij ? (E + 511) / 512 : 0;

  setup_kernel<<<ntypes + 72 + nxe, 256, 0, stream>>>(
      emb, Wlin, blin, Wrbf, ei, ej, x, ntypes, E, P, W3, WrbfB, xij);

  (void)hipFuncSetAttribute(reinterpret_cast<const void*>(&edge_kernel),
                            hipFuncAttributeMaxDynamicSharedMemorySize, LDS_BYTES);

  const int ntile = (E + 127) / 128;
  const int nblk  = ntile < 256 ? ntile : 256;
  edge_kernel<<<nblk, 512, LDS_BYTES, stream>>>(
      rbf, ei, ej, x, WrbfB, brbf, P, W3, use_xij ? xij : nullptr, out, E, ntile, use_xij);
}